// Round 8
// baseline (40.345 us; speedup 1.0000x reference)
//
#include <hip/hip_runtime.h>
#include <hip/hip_bf16.h>
#include <stdint.h>

// Problem constants (from reference)
#define IN_F   4096
#define OUT_F  4096
#define NGRP   32
#define NBLK   32
#define GSZ    128
#define OFI    128
#define WPB    1536          // int32 words per (group, out-block)
#define M_TOK  128
#define KSPLIT 8

typedef __attribute__((ext_vector_type(8))) short bf16x8;
typedef __attribute__((ext_vector_type(4))) float f32x4;

// one-instruction packed f32x2 -> bf16x2 (RNE), gfx950
static __device__ __forceinline__ unsigned cvt_pk_bf16(float lo, float hi) {
    unsigned r;
    asm("v_cvt_pk_bf16_f32 %0, %1, %2" : "=v"(r) : "v"(lo), "v"(hi));
    return r;
}

static __device__ __forceinline__ float u_as_f(unsigned u) {
    union { unsigned u; float f; } v; v.u = u; return v.f;
}

// ---------------------------------------------------------------------------
// Prep kernel (3 roles by blockIdx.x):
//   [0,256):    xr[t][i] = bf16(x[t][in_reorder[i]])  8 gathers/thread
//   [256,260):  inv_out[out_reorder[i]] = i
//   [260,388):  A2 = 2*alpha ; Bp = beta - 135*alpha   (exponent-trick bias)
// ---------------------------------------------------------------------------
__global__ __launch_bounds__(256) void k_prep(const float* __restrict__ x,
                                              const int* __restrict__ in_reorder,
                                              const int* __restrict__ out_reorder,
                                              const float* __restrict__ alpha,
                                              const float* __restrict__ beta,
                                              unsigned short* __restrict__ xr,
                                              int* __restrict__ inv_out,
                                              float* __restrict__ A2,
                                              float* __restrict__ Bp) {
    int b = blockIdx.x;
    if (b < 256) {
        int idx = b * 256 + threadIdx.x;          // 0..65535, 8 elems each
        int t  = idx >> 9;
        int i0 = (idx & 511) << 3;
        int4 s0 = *(const int4*)&in_reorder[i0];
        int4 s1 = *(const int4*)&in_reorder[i0 + 4];
        const float* row = x + (size_t)t * IN_F;
        float v0 = row[s0.x], v1 = row[s0.y], v2 = row[s0.z], v3 = row[s0.w];
        float v4 = row[s1.x], v5 = row[s1.y], v6 = row[s1.z], v7 = row[s1.w];
        uint4 pk;
        pk.x = cvt_pk_bf16(v0, v1);
        pk.y = cvt_pk_bf16(v2, v3);
        pk.z = cvt_pk_bf16(v4, v5);
        pk.w = cvt_pk_bf16(v6, v7);
        *(uint4*)&xr[(size_t)t * IN_F + i0] = pk;
    } else if (b < 260) {
        int i0 = ((b - 256) * 256 + threadIdx.x) << 2;   // 0..4095 step 4
        int4 o = *(const int4*)&out_reorder[i0];
        inv_out[o.x] = i0;
        inv_out[o.y] = i0 + 1;
        inv_out[o.z] = i0 + 2;
        inv_out[o.w] = i0 + 3;
    } else {
        int idx = ((b - 260) * 256 + threadIdx.x) << 2;  // 0..131068 step 4
        float4 a = *(const float4*)&alpha[idx];
        float4 bt = *(const float4*)&beta[idx];
        float4 a2 = make_float4(2.f * a.x, 2.f * a.y, 2.f * a.z, 2.f * a.w);
        float4 bp = make_float4(bt.x - 135.f * a.x, bt.y - 135.f * a.y,
                                bt.z - 135.f * a.z, bt.w - 135.f * a.w);
        *(float4*)&A2[idx] = a2;
        *(float4*)&Bp[idx] = bp;
    }
}

// ---------------------------------------------------------------------------
// Fused dequant + split-K bf16 MFMA GEMM, v2.
//   Cpart[ks][t][c] = sum_{k in ks-chunk} xr[t][k] * W[k][c]   (f32)
// Block: 256 threads, 4 waves as 2x2, wave-tile 64x64, block-tile 128x128.
// Grid (32 nb, 8 ks) = 256 blocks = 1/CU. K-step 128 (one quant group).
// A: direct global->register bf16x8 loads (xr is L2-resident, no LDS).
// B: dequantized into double-buffered XOR-swizzled LDS; ONE barrier/tile.
// qweight words ping-pong prefetched one tile ahead.
// ---------------------------------------------------------------------------
__global__ __launch_bounds__(256, 1) void k_fused(const unsigned short* __restrict__ xr,
                                                  const int* __restrict__ qweight,
                                                  const float* __restrict__ A2,
                                                  const float* __restrict__ Bp,
                                                  const int* __restrict__ offset,
                                                  float* __restrict__ Cpart) {
    __shared__ unsigned short Blds[2][OFI * 128];   // 2 x 32 KB
    const int nb  = blockIdx.x;            // 0..31
    const int ks  = blockIdx.y;            // 0..7
    const int n0  = nb * OFI;              // global col base
    const int tid = threadIdx.x;
    const int l   = tid & 63;
    const int wid = tid >> 6;              // 0..3
    const int wm  = wid >> 1;              // row half (64 rows)
    const int wn  = wid & 1;               // col half (64 cols)

    // dequant role: io-pair p (0..63), word-quarter wc (0..3)
    const int p   = tid >> 2;
    const int wc  = tid & 3;
    const int io0 = 2 * p;

    f32x4 acc[4][4] = {};

    const int g0 = ks * 4;                 // first quant group of this split
    int w[2][6];

    // load words for tile 0
    {
        const int* q = qweight + offset[g0 * NBLK + nb];
        w[0][0] = q[ io0      * 4 + wc];
        w[0][1] = q[(io0 + 1) * 4 + wc];
        w[0][2] = q[ io0      * 4 + wc + 512];
        w[0][3] = q[(io0 + 1) * 4 + wc + 512];
        w[0][4] = q[ io0      * 4 + wc + 1024];
        w[0][5] = q[(io0 + 1) * 4 + wc + 1024];
    }

    // dequant macro body: group g, words ww -> Blds[buf]
    #define DEQUANT(gg, ww, buf)                                                     \
    {                                                                                \
        const float* a2 = A2 + (gg) * OUT_F + n0 + wc * 32;                          \
        const float* bp = Bp + (gg) * OUT_F + n0 + wc * 32;                          \
        unsigned* B32 = (unsigned*)Blds[buf];                                        \
        _Pragma("unroll")                                                            \
        for (int j = 0; j < 32; ++j) {                                               \
            int col = wc * 32 + j;                                                   \
            float sa = a2[j];                                                        \
            float sb = bp[j];                                                        \
            unsigned na  = ((ww[0] >> j) & 1) | (((ww[2] >> j) & 1) << 1)            \
                         | (((ww[4] >> j) & 1) << 2);                                \
            unsigned nbq = ((ww[1] >> j) & 1) | (((ww[3] >> j) & 1) << 1)            \
                         | (((ww[5] >> j) & 1) << 2);                                \
            float va = fmaf(u_as_f(0x42800000u | (na  << 17)), sa, sb);              \
            float vb = fmaf(u_as_f(0x42800000u | (nbq << 17)), sa, sb);              \
            B32[col * 64 + (((p >> 2) ^ (col & 15)) << 2) + (p & 3)]                 \
                = cvt_pk_bf16(va, vb);                                               \
        }                                                                            \
    }

    // prologue: dequant tile 0, prefetch words for tile 1
    DEQUANT(g0, w[0], 0);
    {
        const int* q = qweight + offset[(g0 + 1) * NBLK + nb];
        w[1][0] = q[ io0      * 4 + wc];
        w[1][1] = q[(io0 + 1) * 4 + wc];
        w[1][2] = q[ io0      * 4 + wc + 512];
        w[1][3] = q[(io0 + 1) * 4 + wc + 512];
        w[1][4] = q[ io0      * 4 + wc + 1024];
        w[1][5] = q[(io0 + 1) * 4 + wc + 1024];
    }
    __syncthreads();

    #pragma unroll
    for (int kt = 0; kt < 4; ++kt) {
        // dequant next tile into the other buffer (independent of this tile's MFMA)
        if (kt < 3)
            DEQUANT(g0 + kt + 1, w[(kt + 1) & 1], (kt + 1) & 1);
        // prefetch words for tile kt+2
        if (kt < 2) {
            const int* q = qweight + offset[(g0 + kt + 2) * NBLK + nb];
            w[kt & 1][0] = q[ io0      * 4 + wc];
            w[kt & 1][1] = q[(io0 + 1) * 4 + wc];
            w[kt & 1][2] = q[ io0      * 4 + wc + 512];
            w[kt & 1][3] = q[(io0 + 1) * 4 + wc + 512];
            w[kt & 1][4] = q[ io0      * 4 + wc + 1024];
            w[kt & 1][5] = q[(io0 + 1) * 4 + wc + 1024];
        }

        // MFMA over tile kt: A from global (L2), B from Blds[kt&1]
        const int k0 = (g0 + kt) * GSZ;
        const unsigned short* Bl = Blds[kt & 1];
        #pragma unroll
        for (int kk = 0; kk < 4; ++kk) {
            const int cb = kk * 4 + (l >> 4);
            bf16x8 af[4], bfr[4];
            #pragma unroll
            for (int m = 0; m < 4; ++m) {
                int row = wm * 64 + m * 16 + (l & 15);
                af[m] = *(const bf16x8*)&xr[(size_t)row * IN_F + k0 + (cb << 3)];
            }
            #pragma unroll
            for (int nn = 0; nn < 4; ++nn) {
                int colr = wn * 64 + nn * 16 + (l & 15);
                bfr[nn] = *(const bf16x8*)&Bl[colr * 128 + ((cb ^ (colr & 15)) << 3)];
            }
            #pragma unroll
            for (int m = 0; m < 4; ++m)
                #pragma unroll
                for (int nn = 0; nn < 4; ++nn)
                    acc[m][nn] = __builtin_amdgcn_mfma_f32_16x16x32_bf16(
                        af[m], bfr[nn], acc[m][nn], 0, 0, 0);
        }
        if (kt < 3) __syncthreads();   // B[kt+1] writes drained; readers of Blds[kt&1] done
    }
    #undef DEQUANT

    // ---- epilogue: per-wave 64x64 tile -> f32 Cpart[ks] ----
    float* Cb = Cpart + (size_t)ks * (M_TOK * OUT_F);
    #pragma unroll
    for (int m = 0; m < 4; ++m) {
        int row = wm * 64 + m * 16 + ((l >> 4) << 2);
        #pragma unroll
        for (int nn = 0; nn < 4; ++nn) {
            int col = n0 + wn * 64 + nn * 16 + (l & 15);
            #pragma unroll
            for (int r = 0; r < 4; ++r)
                Cb[(size_t)(row + r) * OUT_F + col] = acc[m][nn][r];
        }
    }
}

// ---------------------------------------------------------------------------
// Reduce: out[t][inv_out[c]] = sum_ks Cpart[ks][t][c]
//   coalesced float4 reads, scattered 4B writes (L2 merges lines).
// ---------------------------------------------------------------------------
__global__ __launch_bounds__(256) void k_reduce(const float* __restrict__ Cpart,
                                                const int* __restrict__ inv_out,
                                                float* __restrict__ out) {
    int idx = blockIdx.x * 256 + threadIdx.x;   // 0..131071, 4 cols each
    int t  = idx >> 10;
    int c0 = (idx & 1023) << 2;
    float4 s = make_float4(0.f, 0.f, 0.f, 0.f);
    #pragma unroll
    for (int ks = 0; ks < KSPLIT; ++ks) {
        float4 v = *(const float4*)&Cpart[(size_t)ks * (M_TOK * OUT_F) + (size_t)t * OUT_F + c0];
        s.x += v.x; s.y += v.y; s.z += v.z; s.w += v.w;
    }
    const int* op = &inv_out[c0];
    float* row = out + (size_t)t * OUT_F;
    row[op[0]] = s.x;
    row[op[1]] = s.y;
    row[op[2]] = s.z;
    row[op[3]] = s.w;
}

// ---------------------------------------------------------------------------
extern "C" void kernel_launch(void* const* d_in, const int* in_sizes, int n_in,
                              void* d_out, int out_size, void* d_ws, size_t ws_size,
                              hipStream_t stream) {
    const float* x           = (const float*)d_in[0];
    const int*   qweight     = (const int*)d_in[1];
    const float* alpha       = (const float*)d_in[2];
    const float* beta        = (const float*)d_in[3];
    // d_in[4] = block_bitwidth (uniform 3, unused)
    const int*   offset      = (const int*)d_in[5];
    const int*   in_reorder  = (const int*)d_in[6];
    const int*   out_reorder = (const int*)d_in[7];
    float* out = (float*)d_out;

    // workspace: xr (1MB) | Cpart (16MB) | inv_out (16KB) | A2 (512KB) | Bp (512KB)
    char* ws = (char*)d_ws;
    unsigned short* xr      = (unsigned short*)ws;
    float*          Cpart   = (float*)(ws + (1u << 20));
    int*            inv_out = (int*)(ws + (1u << 20) + (16u << 20));
    float*          A2      = (float*)(ws + (1u << 20) + (16u << 20) + (16u << 10));
    float*          Bp      = A2 + NGRP * OUT_F;

    k_prep<<<dim3(388), dim3(256), 0, stream>>>(x, in_reorder, out_reorder,
                                                alpha, beta, xr, inv_out, A2, Bp);
    k_fused<<<dim3(32, KSPLIT), dim3(256), 0, stream>>>(xr, qweight, A2, Bp, offset, Cpart);
    k_reduce<<<dim3(512), dim3(256), 0, stream>>>(Cpart, inv_out, out);
}